// Round 10
// baseline (370.121 us; speedup 1.0000x reference)
//
#include <hip/hip_runtime.h>
#include <hip/hip_bf16.h>

// GAT on line graph. Pipeline (round 10):
//   k_prevs : Btr[c][kap]=0.25*W bf16 ; vs[8][64]=W^T@att ; c0 = wb + bias@wgt^T
//   k_fused : heterogeneous grid: cast blocks (x->bf16 xb + exact fp32
//             a_src/a_dst) paired with fill blocks (CSR bucket, 4 edges/thr).
//   k_agg   : TWO dsts per wave (32 lanes each): width-32 softmax, serial
//             alpha-weighted x-row gather, raw z scattered with coalesced
//             fp32 atomics into agg2[N][256]. NO per-dst epilogue.
//   k_proj2 : m[N][64] = bf16(agg2) @ Btr^T   (one MFMA pass, 256 blocks)
//   k_final1: out = (m/deg) @ wgt^T + c0  (shfl GEMV, as before)

#define CAP 64

using frag16 = __attribute__((ext_vector_type(8))) short;  // 8 bf16
using f32x4  = __attribute__((ext_vector_type(4))) float;
using f32x2  = __attribute__((ext_vector_type(2))) float;

__device__ __forceinline__ unsigned short f2bf(float f) {
  union { float f; unsigned u; } v; v.f = f;
  return (unsigned short)((v.u + 0x8000u) >> 16);
}
__device__ __forceinline__ float bflo(unsigned u) {
  union { unsigned u; float f; } v; v.u = u << 16; return v.f;
}
__device__ __forceinline__ float bfhi(unsigned u) {
  union { unsigned u; float f; } v; v.u = u & 0xffff0000u; return v.f;
}
__device__ __forceinline__ unsigned pkbf(float lo, float hi) {
  union { __hip_bfloat162 b; unsigned u; } v;
  v.b = __float22bfloat162_rn(make_float2(lo, hi));   // v_cvt_pk_bf16_f32
  return v.u;
}

// ---------------- Pass 0: Btr + vs + c0 precompute ----------------
__global__ __launch_bounds__(256) void k_prevs(
    const float* __restrict__ W, const float* __restrict__ att_src,
    const float* __restrict__ att_dst, const float* __restrict__ wgt,
    const float* __restrict__ wb, const float* __restrict__ bias,
    unsigned short* __restrict__ Btr, float* __restrict__ vs,
    float* __restrict__ c0) {
  int t = blockIdx.x * 256 + threadIdx.x;    // 64 blocks -> 16384
  {
    int c = t >> 8, kap = t & 255;           // Btr[c][kap] = 0.25*W[h*64+c][k]
    int h = kap >> 6, k = kap & 63;
    Btr[t] = f2bf(0.25f * W[(size_t)(h * 64 + c) * 64 + k]);
  }
  if (blockIdx.x < 2) {
    int o = blockIdx.x * 256 + threadIdx.x;  // 0..511
    int j = o >> 6, c = o & 63;              // 0..3 src heads, 4..7 dst heads
    const float* att = (j < 4) ? att_src : att_dst;
    int hh = j & 3;
    float s = 0.f;
    for (int ch = 0; ch < 64; ++ch)
      s += W[(size_t)(hh * 64 + ch) * 64 + c] * att[hh * 64 + ch];
    vs[o] = s;
  } else if (blockIdx.x == 2 && threadIdx.x < 64) {
    int c = threadIdx.x;
    float s = wb[c];
    for (int c2 = 0; c2 < 64; ++c2) s += bias[c2] * wgt[c * 64 + c2];
    c0[c] = s;
  }
}

// ---------------- Fused: cast blocks + fill blocks ----------------
__device__ __forceinline__ void cast_body(
    const float* __restrict__ x, const float* __restrict__ vs,
    unsigned short* __restrict__ xb, float* __restrict__ a_src,
    float* __restrict__ a_dst, int bid, float* vsl) {
  const int t = threadIdx.x;
  if (t < 128) ((float4*)vsl)[t] = ((const float4*)vs)[t];
  __syncthreads();
  const int w = t >> 6, lane = t & 63, l15 = lane & 15, l4 = lane >> 4;
  const int row = bid * 64 + w * 16 + l15;

  // lane's 16 dims: l4*16 .. +15
  const float4* xp = (const float4*)(x + (size_t)row * 64 + l4 * 16);
  float4 v0 = xp[0], v1 = xp[1], v2 = xp[2], v3 = xp[3];
  float xa[16] = {v0.x, v0.y, v0.z, v0.w, v1.x, v1.y, v1.z, v1.w,
                  v2.x, v2.y, v2.z, v2.w, v3.x, v3.y, v3.z, v3.w};

  // pack bf16 pairs (even dim = lo, odd = hi)
  uint2* dst = (uint2*)(xb + (size_t)row * 64 + l4 * 16);
  dst[0] = make_uint2(pkbf(xa[0], xa[1]),  pkbf(xa[2], xa[3]));
  dst[1] = make_uint2(pkbf(xa[4], xa[5]),  pkbf(xa[6], xa[7]));
  dst[2] = make_uint2(pkbf(xa[8], xa[9]),  pkbf(xa[10], xa[11]));
  dst[3] = make_uint2(pkbf(xa[12], xa[13]), pkbf(xa[14], xa[15]));

  // exact fp32 attention dots (partial over 16 dims, reduce across l4)
  float pj[8];
#pragma unroll
  for (int j = 0; j < 8; ++j) {
    const float4* q = (const float4*)(vsl + j * 64 + l4 * 16);
    float4 q0 = q[0], q1 = q[1], q2 = q[2], q3 = q[3];
    float s = xa[0] * q0.x + xa[1] * q0.y + xa[2] * q0.z + xa[3] * q0.w
            + xa[4] * q1.x + xa[5] * q1.y + xa[6] * q1.z + xa[7] * q1.w
            + xa[8] * q2.x + xa[9] * q2.y + xa[10] * q2.z + xa[11] * q2.w
            + xa[12] * q3.x + xa[13] * q3.y + xa[14] * q3.z + xa[15] * q3.w;
    s += __shfl_xor(s, 16, 64);
    s += __shfl_xor(s, 32, 64);
    pj[j] = s;
  }
  if (l4 == 0) {
    *(float4*)&a_src[(size_t)row * 4] = make_float4(pj[0], pj[1], pj[2], pj[3]);
    *(float4*)&a_dst[(size_t)row * 4] = make_float4(pj[4], pj[5], pj[6], pj[7]);
  }
}

__device__ __forceinline__ void fill_body(
    const int* __restrict__ ei, int M, int E,
    int* __restrict__ cnt, int* __restrict__ csr, int bid) {
  const int Mtot = M + E;
  const int base = bid * 1024 + threadIdx.x;
  int mm[4], ss[4], dd[4];
#pragma unroll
  for (int i = 0; i < 4; ++i) {
    int m = base + i * 256;
    mm[i] = m;
    if (m < Mtot) {
      if (m < M) { ss[i] = ei[m]; dd[i] = ei[M + m]; }
      else       { ss[i] = m - M; dd[i] = m - M; }   // self loop
    }
  }
  int pos[4];
#pragma unroll
  for (int i = 0; i < 4; ++i)
    if (mm[i] < Mtot) pos[i] = atomicAdd(&cnt[dd[i]], 1);
#pragma unroll
  for (int i = 0; i < 4; ++i)
    if (mm[i] < Mtot && pos[i] < CAP) csr[(size_t)dd[i] * CAP + pos[i]] = ss[i];
}

__global__ __launch_bounds__(256, 4) void k_fused(
    const float* __restrict__ x, const float* __restrict__ vs,
    unsigned short* __restrict__ xb,
    float* __restrict__ a_src, float* __restrict__ a_dst,
    const int* __restrict__ ei, int M, int E,
    int* __restrict__ cnt, int* __restrict__ csr,
    int ncast, int nfill) {
  __shared__ float vsl[512];
  const int bid = blockIdx.x;
  int npair = 2 * min(ncast, nfill);
  if (bid < npair) {
    if (bid & 1) cast_body(x, vs, xb, a_src, a_dst, bid >> 1, vsl);
    else         fill_body(ei, M, E, cnt, csr, bid >> 1);
  } else {
    int r = bid - npair;
    if (nfill > ncast) fill_body(ei, M, E, cnt, csr, ncast + r);
    else               cast_body(x, vs, xb, a_src, a_dst, ncast + r, vsl);
  }
}

// ------- Aggregation: 2 dsts/wave, width-32 softmax + gather + z-scatter ----
__global__ __launch_bounds__(256) void k_agg(
    const unsigned short* __restrict__ xb, const float4* __restrict__ a_src,
    const float4* __restrict__ a_dst, const int* __restrict__ cnt,
    const int* __restrict__ csr, const int* __restrict__ rows,
    float* __restrict__ agg2, int* __restrict__ degc, int E) {
  __shared__ float4 alds[8 * 64];
  __shared__ int    olds[8 * 64];        // pre-scaled byte offsets: src*128
  const int w = threadIdx.x >> 6, lane = threadIdx.x & 63;
  const int j = lane >> 5, d2 = lane & 31;
  const int li = w * 2 + j;              // local dst 0..7
  const int e = blockIdx.x * 8 + li;     // grid exactly E/8

  int deg = cnt[e];
  if (deg > CAP) deg = CAP;
  float4 ad = a_dst[e];

  // slot A = d2, slot B = d2 + 32
  float exA0 = 0.f, exA1 = 0.f, exA2 = 0.f, exA3 = 0.f;
  float exB0 = 0.f, exB1 = 0.f, exB2 = 0.f, exB3 = 0.f;
  int sA = 0, sB = 0;
  if (d2 < deg) {
    sA = csr[(size_t)e * CAP + d2];
    float4 as = a_src[sA];
    float l0 = as.x + ad.x; l0 = l0 > 0.f ? l0 : 0.2f * l0;
    float l1 = as.y + ad.y; l1 = l1 > 0.f ? l1 : 0.2f * l1;
    float l2 = as.z + ad.z; l2 = l2 > 0.f ? l2 : 0.2f * l2;
    float l3 = as.w + ad.w; l3 = l3 > 0.f ? l3 : 0.2f * l3;
    exA0 = __expf(l0); exA1 = __expf(l1); exA2 = __expf(l2); exA3 = __expf(l3);
  }
  if (deg > 32) {
    if (d2 + 32 < deg) {
      sB = csr[(size_t)e * CAP + d2 + 32];
      float4 as = a_src[sB];
      float l0 = as.x + ad.x; l0 = l0 > 0.f ? l0 : 0.2f * l0;
      float l1 = as.y + ad.y; l1 = l1 > 0.f ? l1 : 0.2f * l1;
      float l2 = as.z + ad.z; l2 = l2 > 0.f ? l2 : 0.2f * l2;
      float l3 = as.w + ad.w; l3 = l3 > 0.f ? l3 : 0.2f * l3;
      exB0 = __expf(l0); exB1 = __expf(l1); exB2 = __expf(l2); exB3 = __expf(l3);
    }
  }
  // width-32 reduce (xor offsets 1..16 stay within each half)
  float s0 = exA0 + exB0, s1 = exA1 + exB1, s2 = exA2 + exB2, s3 = exA3 + exB3;
#pragma unroll
  for (int off = 16; off > 0; off >>= 1) {
    s0 += __shfl_xor(s0, off, 64);
    s1 += __shfl_xor(s1, off, 64);
    s2 += __shfl_xor(s2, off, 64);
    s3 += __shfl_xor(s3, off, 64);
  }
  float i0 = 1.f / (s0 + 1e-16f), i1 = 1.f / (s1 + 1e-16f);
  float i2 = 1.f / (s2 + 1e-16f), i3 = 1.f / (s3 + 1e-16f);

  alds[li * 64 + d2] = make_float4(exA0 * i0, exA1 * i1, exA2 * i2, exA3 * i3);
  olds[li * 64 + d2] = sA << 7;          // x row = 128 bytes
  if (deg > 32) {
    alds[li * 64 + d2 + 32] =
        make_float4(exB0 * i0, exB1 * i1, exB2 * i2, exB3 * i3);
    olds[li * 64 + d2 + 32] = sB << 7;
  }
  __syncthreads();

  // gather: lane (j,d2) accumulates z[h][2*d2 .. 2*d2+1] for its dst
  const char* xbase = (const char*)xb + d2 * 4;
  const int kb = li * 64;
  f32x2 zz0 = {0.f, 0.f}, zz1 = {0.f, 0.f}, zz2 = {0.f, 0.f}, zz3 = {0.f, 0.f};
  for (int k = 0; k < deg; ++k) {
    float4 A = alds[kb + k];
    unsigned v = *(const unsigned*)(xbase + (size_t)(unsigned)olds[kb + k]);
    f32x2 xv; xv.x = bflo(v); xv.y = bfhi(v);
    f32x2 c0_ = {A.x, A.x}, c1_ = {A.y, A.y};
    f32x2 c2_ = {A.z, A.z}, c3_ = {A.w, A.w};
    zz0 += c0_ * xv; zz1 += c1_ * xv; zz2 += c2_ * xv; zz3 += c3_ * xv;
  }

  // scatter raw z into agg2[r][256] (coalesced 256B runs per head row)
  int r = rows[e];
  float* bp2 = agg2 + (size_t)r * 256 + 2 * d2;
  atomicAdd(bp2 + 0,   zz0.x); atomicAdd(bp2 + 1,   zz0.y);
  atomicAdd(bp2 + 64,  zz1.x); atomicAdd(bp2 + 65,  zz1.y);
  atomicAdd(bp2 + 128, zz2.x); atomicAdd(bp2 + 129, zz2.y);
  atomicAdd(bp2 + 192, zz3.x); atomicAdd(bp2 + 193, zz3.y);
  if (d2 == 0) atomicAdd(&degc[r], 1);
}

// ---------------- m[N][64] = bf16(agg2) @ Btr^T ----------------
__global__ __launch_bounds__(256) void k_proj2(
    const float* __restrict__ agg2, const unsigned short* __restrict__ Btr,
    float* __restrict__ m, int N) {
  const int w = threadIdx.x >> 6, lane = threadIdx.x & 63;
  const int l15 = lane & 15, l4 = lane >> 4;
  const int n0 = blockIdx.x * 64 + w * 16;
  const float* ap = agg2 + (size_t)(n0 + l15) * 256 + l4 * 8;
  f32x4 acc[4] = {{0.f, 0.f, 0.f, 0.f}, {0.f, 0.f, 0.f, 0.f},
                  {0.f, 0.f, 0.f, 0.f}, {0.f, 0.f, 0.f, 0.f}};
#pragma unroll
  for (int s = 0; s < 8; ++s) {
    const float4* a4 = (const float4*)(ap + s * 32);
    float4 za = a4[0], zb = a4[1];
    frag16 af;
    unsigned* au = (unsigned*)&af;
    au[0] = pkbf(za.x, za.y); au[1] = pkbf(za.z, za.w);
    au[2] = pkbf(zb.x, zb.y); au[3] = pkbf(zb.z, zb.w);
#pragma unroll
    for (int nt = 0; nt < 4; ++nt) {
      frag16 bfg =
          *(const frag16*)(Btr + (size_t)(nt * 16 + l15) * 256 + s * 32 + l4 * 8);
      acc[nt] = __builtin_amdgcn_mfma_f32_16x16x32_bf16(af, bfg, acc[nt], 0, 0, 0);
    }
  }
  // C map: row = l4*4 + r, col = nt*16 + l15
#pragma unroll
  for (int nt = 0; nt < 4; ++nt)
#pragma unroll
    for (int r = 0; r < 4; ++r)
      m[(size_t)(n0 + l4 * 4 + r) * 64 + nt * 16 + l15] = acc[nt][r];
}

// ---------------- out = (m/deg) @ wgt^T + c0 ----------------
__global__ __launch_bounds__(256) void k_final1(
    const float* __restrict__ m, const int* __restrict__ degc,
    const float* __restrict__ wgt, const float* __restrict__ c0,
    const float* __restrict__ wb, float* __restrict__ out, int N) {
  __shared__ float wtt[64 * 65];
  const int t = threadIdx.x;
#pragma unroll
  for (int i = 0; i < 16; ++i) {
    int idx = t + i * 256;                       // idx = c*64 + k
    wtt[(idx & 63) * 65 + (idx >> 6)] = wgt[idx];
  }
  __syncthreads();
  const int w = t >> 6, lane = t & 63;
  int n = blockIdx.x * 4 + w;
  if (n >= N) return;
  int dg = degc[n];
  float av = dg > 0 ? m[(size_t)n * 64 + lane] / (float)dg : 0.f;
  float o = 0.f;
#pragma unroll
  for (int k = 0; k < 64; ++k) {
    o += __shfl(av, k, 64) * wtt[k * 65 + lane];
  }
  out[(size_t)n * 64 + lane] = dg > 0 ? o + c0[lane] : wb[lane];
}

extern "C" void kernel_launch(void* const* d_in, const int* in_sizes, int n_in,
                              void* d_out, int out_size, void* d_ws, size_t ws_size,
                              hipStream_t stream) {
  const float* x       = (const float*)d_in[0];
  const int*   ei      = (const int*)d_in[1];
  const int*   rows    = (const int*)d_in[2];
  const float* W       = (const float*)d_in[3];
  const float* att_src = (const float*)d_in[4];
  const float* att_dst = (const float*)d_in[5];
  const float* bias    = (const float*)d_in[6];
  const float* wgt     = (const float*)d_in[7];
  const float* wb      = (const float*)d_in[8];

  const int E = in_sizes[0] / 64;     // 131072
  const int M = in_sizes[1] / 2;      // 2097152
  const int N = out_size / 64;        // 16384

  char* p = (char*)d_ws;
  unsigned short* xb = (unsigned short*)p;  p += (size_t)E * 64 * 2;    // 16MB
  int*   csr   = (int*)p;                   p += (size_t)E * CAP * 4;   // 32MB
  float* a_src = (float*)p;                 p += (size_t)E * 4 * 4;     // 2MB
  float* a_dst = (float*)p;                 p += (size_t)E * 4 * 4;     // 2MB
  // cnt, agg2, degc contiguous -> single memset
  int*   cnt   = (int*)p;                   p += (size_t)E * 4;         // 512KB
  float* agg2  = (float*)p;                 p += (size_t)N * 256 * 4;   // 16MB
  int*   degc  = (int*)p;                   p += (size_t)N * 4;         // 64KB
  float* m     = (float*)p;                 p += (size_t)N * 64 * 4;    // 4MB
  unsigned short* Btr = (unsigned short*)p; p += 64 * 256 * 2;          // 32KB
  float* vs    = (float*)p;                 p += 512 * 4;               // 2KB
  float* c0    = (float*)p;                 p += 64 * 4;                // 256B

  hipMemsetAsync(cnt, 0,
                 (size_t)E * 4 + (size_t)N * 256 * 4 + (size_t)N * 4, stream);

  k_prevs<<<64, 256, 0, stream>>>(W, att_src, att_dst, wgt, wb, bias,
                                  Btr, vs, c0);

  const int Mtot = M + E;
  const int ncast = E / 64;                  // 2048
  const int nfill = (Mtot + 1023) / 1024;    // 2176
  k_fused<<<ncast + nfill, 256, 0, stream>>>(
      x, vs, xb, a_src, a_dst, ei, M, E, cnt, csr, ncast, nfill);

  k_agg<<<E / 8, 256, 0, stream>>>(
      xb, (const float4*)a_src, (const float4*)a_dst, cnt, csr,
      rows, agg2, degc, E);

  k_proj2<<<N / 64, 256, 0, stream>>>(agg2, Btr, m, N);

  k_final1<<<(N + 3) / 4, 256, 0, stream>>>(m, degc, wgt, c0, wb,
                                            (float*)d_out, N);
}

// Round 11
// 313.117 us; speedup vs baseline: 1.1821x; 1.1821x over previous
//
#include <hip/hip_runtime.h>
#include <hip/hip_bf16.h>

// GAT on line graph. Pipeline (round 11):
//   k_prevs : Btr bf16 = 0.25*W^T-ish ; vs[8][64]=W^T@att
//   k_fused : heterogeneous grid: cast blocks (x->bf16 xb + exact fp32
//             a_src/a_dst) paired with fill blocks (CSR bucket, 4 edges/thr).
//   k_agg   : per-dst wave softmax; 4-GROUP gather (4 neighbors per load
//             instruction, uint2/lane), no barrier between softmax and gather
//             (wave-private LDS), per-dst MFMA epilogue, 64-wide agg atomics.
//   k_final : scatter-mean normalize + 64x64 linear

#define CAP 64
#define ZST 260   // zl stride: mod32=4 -> 2-way max on epilogue reads (free)

using frag16 = __attribute__((ext_vector_type(8))) short;  // 8 bf16
using f32x4  = __attribute__((ext_vector_type(4))) float;
using f32x2  = __attribute__((ext_vector_type(2))) float;

__device__ __forceinline__ unsigned short f2bf(float f) {
  union { float f; unsigned u; } v; v.f = f;
  return (unsigned short)((v.u + 0x8000u) >> 16);
}
__device__ __forceinline__ float bflo(unsigned u) {
  union { unsigned u; float f; } v; v.u = u << 16; return v.f;
}
__device__ __forceinline__ float bfhi(unsigned u) {
  union { unsigned u; float f; } v; v.u = u & 0xffff0000u; return v.f;
}
__device__ __forceinline__ unsigned pkbf(float lo, float hi) {
  union { __hip_bfloat162 b; unsigned u; } v;
  v.b = __float22bfloat162_rn(make_float2(lo, hi));   // v_cvt_pk_bf16_f32
  return v.u;
}

// ---------------- Pass 0: vs + Btr precompute ----------------
__global__ __launch_bounds__(256) void k_prevs(
    const float* __restrict__ W, const float* __restrict__ att_src,
    const float* __restrict__ att_dst, unsigned short* __restrict__ Btr,
    float* __restrict__ vs) {
  int t = blockIdx.x * 256 + threadIdx.x;    // 64 blocks -> 16384
  {
    int c = t >> 8, kap = t & 255;           // Btr[c][kap] = 0.25*W[h*64+c][k]
    int h = kap >> 6, k = kap & 63;
    Btr[t] = f2bf(0.25f * W[(size_t)(h * 64 + c) * 64 + k]);
  }
  if (blockIdx.x < 2) {
    int o = blockIdx.x * 256 + threadIdx.x;  // 0..511
    int j = o >> 6, c = o & 63;              // 0..3 src heads, 4..7 dst heads
    const float* att = (j < 4) ? att_src : att_dst;
    int hh = j & 3;
    float s = 0.f;
    for (int ch = 0; ch < 64; ++ch)
      s += W[(size_t)(hh * 64 + ch) * 64 + c] * att[hh * 64 + ch];
    vs[o] = s;
  }
}

// ---------------- Fused: cast blocks + fill blocks ----------------
__device__ __forceinline__ void cast_body(
    const float* __restrict__ x, const float* __restrict__ vs,
    unsigned short* __restrict__ xb, float* __restrict__ a_src,
    float* __restrict__ a_dst, int bid, float* vsl) {
  const int t = threadIdx.x;
  if (t < 128) ((float4*)vsl)[t] = ((const float4*)vs)[t];
  __syncthreads();
  const int w = t >> 6, lane = t & 63, l15 = lane & 15, l4 = lane >> 4;
  const int row = bid * 64 + w * 16 + l15;

  // lane's 16 dims: l4*16 .. +15
  const float4* xp = (const float4*)(x + (size_t)row * 64 + l4 * 16);
  float4 v0 = xp[0], v1 = xp[1], v2 = xp[2], v3 = xp[3];
  float xa[16] = {v0.x, v0.y, v0.z, v0.w, v1.x, v1.y, v1.z, v1.w,
                  v2.x, v2.y, v2.z, v2.w, v3.x, v3.y, v3.z, v3.w};

  // pack bf16 pairs (even dim = lo, odd = hi)
  uint2* dst = (uint2*)(xb + (size_t)row * 64 + l4 * 16);
  dst[0] = make_uint2(pkbf(xa[0], xa[1]),  pkbf(xa[2], xa[3]));
  dst[1] = make_uint2(pkbf(xa[4], xa[5]),  pkbf(xa[6], xa[7]));
  dst[2] = make_uint2(pkbf(xa[8], xa[9]),  pkbf(xa[10], xa[11]));
  dst[3] = make_uint2(pkbf(xa[12], xa[13]), pkbf(xa[14], xa[15]));

  // exact fp32 attention dots (partial over 16 dims, reduce across l4)
  float pj[8];
#pragma unroll
  for (int j = 0; j < 8; ++j) {
    const float4* q = (const float4*)(vsl + j * 64 + l4 * 16);
    float4 q0 = q[0], q1 = q[1], q2 = q[2], q3 = q[3];
    float s = xa[0] * q0.x + xa[1] * q0.y + xa[2] * q0.z + xa[3] * q0.w
            + xa[4] * q1.x + xa[5] * q1.y + xa[6] * q1.z + xa[7] * q1.w
            + xa[8] * q2.x + xa[9] * q2.y + xa[10] * q2.z + xa[11] * q2.w
            + xa[12] * q3.x + xa[13] * q3.y + xa[14] * q3.z + xa[15] * q3.w;
    s += __shfl_xor(s, 16, 64);
    s += __shfl_xor(s, 32, 64);
    pj[j] = s;
  }
  if (l4 == 0) {
    *(float4*)&a_src[(size_t)row * 4] = make_float4(pj[0], pj[1], pj[2], pj[3]);
    *(float4*)&a_dst[(size_t)row * 4] = make_float4(pj[4], pj[5], pj[6], pj[7]);
  }
}

__device__ __forceinline__ void fill_body(
    const int* __restrict__ ei, int M, int E,
    int* __restrict__ cnt, int* __restrict__ csr, int bid) {
  const int Mtot = M + E;
  const int base = bid * 1024 + threadIdx.x;
  int mm[4], ss[4], dd[4];
#pragma unroll
  for (int i = 0; i < 4; ++i) {
    int m = base + i * 256;
    mm[i] = m;
    if (m < Mtot) {
      if (m < M) { ss[i] = ei[m]; dd[i] = ei[M + m]; }
      else       { ss[i] = m - M; dd[i] = m - M; }   // self loop
    }
  }
  int pos[4];
#pragma unroll
  for (int i = 0; i < 4; ++i)
    if (mm[i] < Mtot) pos[i] = atomicAdd(&cnt[dd[i]], 1);
#pragma unroll
  for (int i = 0; i < 4; ++i)
    if (mm[i] < Mtot && pos[i] < CAP) csr[(size_t)dd[i] * CAP + pos[i]] = ss[i];
}

__global__ __launch_bounds__(256, 4) void k_fused(
    const float* __restrict__ x, const float* __restrict__ vs,
    unsigned short* __restrict__ xb,
    float* __restrict__ a_src, float* __restrict__ a_dst,
    const int* __restrict__ ei, int M, int E,
    int* __restrict__ cnt, int* __restrict__ csr,
    int ncast, int nfill) {
  __shared__ float vsl[512];
  const int bid = blockIdx.x;
  int npair = 2 * min(ncast, nfill);
  if (bid < npair) {
    if (bid & 1) cast_body(x, vs, xb, a_src, a_dst, bid >> 1, vsl);
    else         fill_body(ei, M, E, cnt, csr, bid >> 1);
  } else {
    int r = bid - npair;
    if (nfill > ncast) fill_body(ei, M, E, cnt, csr, ncast + r);
    else               cast_body(x, vs, xb, a_src, a_dst, ncast + r, vsl);
  }
}

// ------ Aggregation: softmax + 4-group x-gather + per-dst MFMA epilogue -----
__global__ __launch_bounds__(256) void k_agg(
    const unsigned short* __restrict__ xb, const float4* __restrict__ a_src,
    const float4* __restrict__ a_dst, const int* __restrict__ cnt,
    const int* __restrict__ csr, const int* __restrict__ rows,
    const unsigned short* __restrict__ Btr, const float* __restrict__ bias,
    float* __restrict__ agg, int* __restrict__ degc, int E) {
  __shared__ float4 alds[4 * 64];
  __shared__ int    olds[4 * 64];        // pre-scaled byte offsets: src*128
  __shared__ float  zl[4 * ZST];         // [dst wave][kappa], stride 260
  const int w = threadIdx.x >> 6, lane = threadIdx.x & 63;
  const int e = blockIdx.x * 4 + w;      // grid exactly E/4

  int deg = cnt[e];
  if (deg > CAP) deg = CAP;
  float4 ad = a_dst[e];

  int src = 0;
  float ex0 = 0.f, ex1 = 0.f, ex2 = 0.f, ex3 = 0.f;
  if (lane < deg) {
    src = csr[(size_t)e * CAP + lane];
    float4 as = a_src[src];
    float l0 = as.x + ad.x; l0 = l0 > 0.f ? l0 : 0.2f * l0;
    float l1 = as.y + ad.y; l1 = l1 > 0.f ? l1 : 0.2f * l1;
    float l2 = as.z + ad.z; l2 = l2 > 0.f ? l2 : 0.2f * l2;
    float l3 = as.w + ad.w; l3 = l3 > 0.f ? l3 : 0.2f * l3;
    ex0 = __expf(l0); ex1 = __expf(l1); ex2 = __expf(l2); ex3 = __expf(l3);
  }
  float s0 = ex0, s1 = ex1, s2 = ex2, s3 = ex3;
#pragma unroll
  for (int off = 32; off > 0; off >>= 1) {
    s0 += __shfl_xor(s0, off, 64);
    s1 += __shfl_xor(s1, off, 64);
    s2 += __shfl_xor(s2, off, 64);
    s3 += __shfl_xor(s3, off, 64);
  }
  float i0 = 1.f / (s0 + 1e-16f), i1 = 1.f / (s1 + 1e-16f);
  float i2 = 1.f / (s2 + 1e-16f), i3 = 1.f / (s3 + 1e-16f);

  // wave-private staging: no __syncthreads needed (only wave w reads kb=w*64)
  alds[w * 64 + lane] = make_float4(ex0 * i0, ex1 * i1, ex2 * i2, ex3 * i3);
  olds[w * 64 + lane] = src << 7;        // x row = 128 bytes

  // phase 2: 4-group gather. Group g=lane>>4 handles neighbors k=4*it+g;
  // lane i16=lane&15 loads uint2 (dims 4*i16 .. 4*i16+3).
  const int g = lane >> 4, i16 = lane & 15;
  const char* xbase = (const char*)xb + i16 * 8;
  const int kb = w * 64;
  f32x2 zp0 = {0.f, 0.f}, zp1 = {0.f, 0.f}, zp2 = {0.f, 0.f}, zp3 = {0.f, 0.f};
  f32x2 zp4 = {0.f, 0.f}, zp5 = {0.f, 0.f}, zp6 = {0.f, 0.f}, zp7 = {0.f, 0.f};
  const int nq = (deg + 3) >> 2;
#pragma unroll 2
  for (int it = 0; it < nq; ++it) {
    int k = 4 * it + g;                  // k <= 63; alpha=0 beyond deg
    float4 A = alds[kb + k];
    uint2 v = *(const uint2*)(xbase + (size_t)(unsigned)olds[kb + k]);
    f32x2 xv0; xv0.x = bflo(v.x); xv0.y = bfhi(v.x);
    f32x2 xv1; xv1.x = bflo(v.y); xv1.y = bfhi(v.y);
    f32x2 a0 = {A.x, A.x}, a1 = {A.y, A.y}, a2 = {A.z, A.z}, a3 = {A.w, A.w};
    zp0 += a0 * xv0; zp1 += a0 * xv1;
    zp2 += a1 * xv0; zp3 += a1 * xv1;
    zp4 += a2 * xv0; zp5 += a2 * xv1;
    zp6 += a3 * xv0; zp7 += a3 * xv1;
  }
  // reduce across the 4 groups
#define RED(z_) { \
    z_.x += __shfl_xor(z_.x, 16, 64); z_.y += __shfl_xor(z_.y, 16, 64); \
    z_.x += __shfl_xor(z_.x, 32, 64); z_.y += __shfl_xor(z_.y, 32, 64); }
  RED(zp0) RED(zp1) RED(zp2) RED(zp3) RED(zp4) RED(zp5) RED(zp6) RED(zp7)
#undef RED

  // phase 3: stage z (lanes 0..15; lane i16 holds dims 4*i16..4*i16+3)
  if (lane < 16) {
    float* zw = &zl[w * ZST + 4 * i16];
    *(float4*)&zw[0]   = make_float4(zp0.x, zp0.y, zp1.x, zp1.y);
    *(float4*)&zw[64]  = make_float4(zp2.x, zp2.y, zp3.x, zp3.y);
    *(float4*)&zw[128] = make_float4(zp4.x, zp4.y, zp5.x, zp5.y);
    *(float4*)&zw[192] = make_float4(zp6.x, zp6.y, zp7.x, zp7.y);
  }
  __syncthreads();

  // epilogue: out[4 dst][64 c] = z @ Btr^T ; wave w -> col tile w (c=w*16+l15)
  const int l15 = lane & 15, l4 = lane >> 4;
  const int drow = l15 & 3;              // A row content: dst index (dups ok)
  const unsigned short* bp = Btr + (size_t)(w * 16 + l15) * 256 + l4 * 8;
  const float* zp = &zl[drow * ZST + l4 * 8];
  f32x4 acc = {0.f, 0.f, 0.f, 0.f};
#pragma unroll
  for (int kk = 0; kk < 8; ++kk) {
    const float4* z4p = (const float4*)(zp + kk * 32);
    float4 za = z4p[0], zb = z4p[1];
    frag16 af;
    unsigned* au = (unsigned*)&af;
    au[0] = pkbf(za.x, za.y);
    au[1] = pkbf(za.z, za.w);
    au[2] = pkbf(zb.x, zb.y);
    au[3] = pkbf(zb.z, zb.w);
    frag16 bfg = *(const frag16*)(bp + kk * 32);
    acc = __builtin_amdgcn_mfma_f32_16x16x32_bf16(af, bfg, acc, 0, 0, 0);
  }
  // C map: row = l4*4 + reg, col = l15 -> rows 0..3 live in lanes l4==0
  if (l4 == 0) {
    int ccol = w * 16 + l15;
    float bs = bias[ccol];
#pragma unroll
    for (int r = 0; r < 4; ++r) {
      int ee = blockIdx.x * 4 + r;
      atomicAdd(&agg[(size_t)rows[ee] * 64 + ccol], acc[r] + bs);
    }
  }
  if (lane == 0) atomicAdd(&degc[rows[e]], 1);
}

// ---------------- scatter-mean normalize + final linear ----------------
__global__ __launch_bounds__(256) void k_final(
    const float* __restrict__ agg, const int* __restrict__ degc,
    const float* __restrict__ wgt, const float* __restrict__ wb,
    float* __restrict__ out, int N) {
  __shared__ float wtt[64 * 65];
  const int t = threadIdx.x;
#pragma unroll
  for (int i = 0; i < 16; ++i) {
    int idx = t + i * 256;                       // idx = c*64 + k
    wtt[(idx & 63) * 65 + (idx >> 6)] = wgt[idx];
  }
  __syncthreads();
  const int w = t >> 6, lane = t & 63;
  int n = blockIdx.x * 4 + w;
  if (n >= N) return;
  int dg = degc[n];
  float av = dg > 0 ? agg[(size_t)n * 64 + lane] / (float)dg : 0.f;
  float o = 0.f;
#pragma unroll
  for (int k = 0; k < 64; ++k) {
    o += __shfl(av, k, 64) * wtt[k * 65 + lane];
  }
  out[(size_t)n * 64 + lane] = o + wb[lane];
}

extern "C" void kernel_launch(void* const* d_in, const int* in_sizes, int n_in,
                              void* d_out, int out_size, void* d_ws, size_t ws_size,
                              hipStream_t stream) {
  const float* x       = (const float*)d_in[0];
  const int*   ei      = (const int*)d_in[1];
  const int*   rows    = (const int*)d_in[2];
  const float* W       = (const float*)d_in[3];
  const float* att_src = (const float*)d_in[4];
  const float* att_dst = (const float*)d_in[5];
  const float* bias    = (const float*)d_in[6];
  const float* wgt     = (const float*)d_in[7];
  const float* wb      = (const float*)d_in[8];

  const int E = in_sizes[0] / 64;     // 131072
  const int M = in_sizes[1] / 2;      // 2097152
  const int N = out_size / 64;        // 16384

  char* p = (char*)d_ws;
  unsigned short* xb = (unsigned short*)p;  p += (size_t)E * 64 * 2;   // 16MB
  int*   csr   = (int*)p;                   p += (size_t)E * CAP * 4;  // 32MB
  float* a_src = (float*)p;                 p += (size_t)E * 4 * 4;    // 2MB
  float* a_dst = (float*)p;                 p += (size_t)E * 4 * 4;    // 2MB
  // cnt, agg, degc contiguous -> single memset
  int*   cnt   = (int*)p;                   p += (size_t)E * 4;        // 512KB
  float* agg   = (float*)p;                 p += (size_t)N * 64 * 4;   // 4MB
  int*   degc  = (int*)p;                   p += (size_t)N * 4;        // 64KB
  unsigned short* Btr = (unsigned short*)p; p += 64 * 256 * 2;         // 32KB
  float* vs    = (float*)p;                 p += 512 * 4;              // 2KB

  hipMemsetAsync(cnt, 0,
                 (size_t)E * 4 + (size_t)N * 64 * 4 + (size_t)N * 4, stream);

  k_prevs<<<64, 256, 0, stream>>>(W, att_src, att_dst, Btr, vs);

  const int Mtot = M + E;
  const int ncast = E / 64;                  // 2048
  const int nfill = (Mtot + 1023) / 1024;    // 2176
  k_fused<<<ncast + nfill, 256, 0, stream>>>(
      x, vs, xb, a_src, a_dst, ei, M, E, cnt, csr, ncast, nfill);

  k_agg<<<E / 4, 256, 0, stream>>>(
      xb, (const float4*)a_src, (const float4*)a_dst, cnt, csr,
      rows, Btr, bias, agg, degc, E);

  k_final<<<(N + 3) / 4, 256, 0, stream>>>(agg, degc, wgt, wb, (float*)d_out, N);
}

// Round 12
// 252.312 us; speedup vs baseline: 1.4669x; 1.2410x over previous
//
#include <hip/hip_runtime.h>
#include <hip/hip_bf16.h>

// GAT on line graph. Pipeline (round 12):
//   k_prevs : Btr[c][kap]=0.25*W bf16 ; vs[8][64]=W^T@att
//   k_fused : heterogeneous grid: adot blocks (exact fp32 a_src/a_dst from x)
//             paired with fill blocks (CSR bucket, 4 edges/thr).
//   k_agg   : 2 dsts per wave (one per 32-lane half): width-32 softmax,
//             4-deep-pipelined fp32 x-row gather (no parity reduce),
//             zl[8][260] staging, 8-dst MFMA epilogue, 64-wide agg atomics.
//   k_final : scatter-mean normalize + 64x64 linear

#define CAP 64
#define ZST 260   // zl stride: mod32=4 -> benign bank pattern on b128 reads

using frag16 = __attribute__((ext_vector_type(8))) short;  // 8 bf16
using f32x4  = __attribute__((ext_vector_type(4))) float;
using f32x2  = __attribute__((ext_vector_type(2))) float;

__device__ __forceinline__ unsigned short f2bf(float f) {
  union { float f; unsigned u; } v; v.f = f;
  return (unsigned short)((v.u + 0x8000u) >> 16);
}
__device__ __forceinline__ unsigned pkbf(float lo, float hi) {
  union { __hip_bfloat162 b; unsigned u; } v;
  v.b = __float22bfloat162_rn(make_float2(lo, hi));   // v_cvt_pk_bf16_f32
  return v.u;
}

// ---------------- Pass 0: vs + Btr precompute ----------------
__global__ __launch_bounds__(256) void k_prevs(
    const float* __restrict__ W, const float* __restrict__ att_src,
    const float* __restrict__ att_dst, unsigned short* __restrict__ Btr,
    float* __restrict__ vs) {
  int t = blockIdx.x * 256 + threadIdx.x;    // 64 blocks -> 16384
  {
    int c = t >> 8, kap = t & 255;           // Btr[c][kap] = 0.25*W[h*64+c][k]
    int h = kap >> 6, k = kap & 63;
    Btr[t] = f2bf(0.25f * W[(size_t)(h * 64 + c) * 64 + k]);
  }
  if (blockIdx.x < 2) {
    int o = blockIdx.x * 256 + threadIdx.x;  // 0..511
    int j = o >> 6, c = o & 63;              // 0..3 src heads, 4..7 dst heads
    const float* att = (j < 4) ? att_src : att_dst;
    int hh = j & 3;
    float s = 0.f;
    for (int ch = 0; ch < 64; ++ch)
      s += W[(size_t)(hh * 64 + ch) * 64 + c] * att[hh * 64 + ch];
    vs[o] = s;
  }
}

// ---------------- Fused: a-dot blocks + fill blocks ----------------
__device__ __forceinline__ void adot_body(
    const float* __restrict__ x, const float* __restrict__ vs,
    float* __restrict__ a_src, float* __restrict__ a_dst, int bid,
    float* vsl) {
  const int t = threadIdx.x;
  if (t < 128) ((float4*)vsl)[t] = ((const float4*)vs)[t];
  __syncthreads();
  const int w = t >> 6, lane = t & 63, l15 = lane & 15, l4 = lane >> 4;
  const int row = bid * 64 + w * 16 + l15;

  // lane's 16 dims: l4*16 .. +15
  const float4* xp = (const float4*)(x + (size_t)row * 64 + l4 * 16);
  float4 v0 = xp[0], v1 = xp[1], v2 = xp[2], v3 = xp[3];
  float xa[16] = {v0.x, v0.y, v0.z, v0.w, v1.x, v1.y, v1.z, v1.w,
                  v2.x, v2.y, v2.z, v2.w, v3.x, v3.y, v3.z, v3.w};

  // exact fp32 attention dots (partial over 16 dims, reduce across l4)
  float pj[8];
#pragma unroll
  for (int j = 0; j < 8; ++j) {
    const float4* q = (const float4*)(vsl + j * 64 + l4 * 16);
    float4 q0 = q[0], q1 = q[1], q2 = q[2], q3 = q[3];
    float s = xa[0] * q0.x + xa[1] * q0.y + xa[2] * q0.z + xa[3] * q0.w
            + xa[4] * q1.x + xa[5] * q1.y + xa[6] * q1.z + xa[7] * q1.w
            + xa[8] * q2.x + xa[9] * q2.y + xa[10] * q2.z + xa[11] * q2.w
            + xa[12] * q3.x + xa[13] * q3.y + xa[14] * q3.z + xa[15] * q3.w;
    s += __shfl_xor(s, 16, 64);
    s += __shfl_xor(s, 32, 64);
    pj[j] = s;
  }
  if (l4 == 0) {
    *(float4*)&a_src[(size_t)row * 4] = make_float4(pj[0], pj[1], pj[2], pj[3]);
    *(float4*)&a_dst[(size_t)row * 4] = make_float4(pj[4], pj[5], pj[6], pj[7]);
  }
}

__device__ __forceinline__ void fill_body(
    const int* __restrict__ ei, int M, int E,
    int* __restrict__ cnt, int* __restrict__ csr, int bid) {
  const int Mtot = M + E;
  const int base = bid * 1024 + threadIdx.x;
  int mm[4], ss[4], dd[4];
#pragma unroll
  for (int i = 0; i < 4; ++i) {
    int m = base + i * 256;
    mm[i] = m;
    if (m < Mtot) {
      if (m < M) { ss[i] = ei[m]; dd[i] = ei[M + m]; }
      else       { ss[i] = m - M; dd[i] = m - M; }   // self loop
    }
  }
  int pos[4];
#pragma unroll
  for (int i = 0; i < 4; ++i)
    if (mm[i] < Mtot) pos[i] = atomicAdd(&cnt[dd[i]], 1);
#pragma unroll
  for (int i = 0; i < 4; ++i)
    if (mm[i] < Mtot && pos[i] < CAP) csr[(size_t)dd[i] * CAP + pos[i]] = ss[i];
}

__global__ __launch_bounds__(256, 4) void k_fused(
    const float* __restrict__ x, const float* __restrict__ vs,
    float* __restrict__ a_src, float* __restrict__ a_dst,
    const int* __restrict__ ei, int M, int E,
    int* __restrict__ cnt, int* __restrict__ csr,
    int ncast, int nfill) {
  __shared__ float vsl[512];
  const int bid = blockIdx.x;
  int npair = 2 * min(ncast, nfill);
  if (bid < npair) {
    if (bid & 1) adot_body(x, vs, a_src, a_dst, bid >> 1, vsl);
    else         fill_body(ei, M, E, cnt, csr, bid >> 1);
  } else {
    int r = bid - npair;
    if (nfill > ncast) fill_body(ei, M, E, cnt, csr, ncast + r);
    else               adot_body(x, vs, a_src, a_dst, ncast + r, vsl);
  }
}

// --- Aggregation: 2 dsts/wave softmax + pipelined fp32 gather + MFMA -------
__global__ __launch_bounds__(256) void k_agg(
    const float* __restrict__ x, const float4* __restrict__ a_src,
    const float4* __restrict__ a_dst, const int* __restrict__ cnt,
    const int* __restrict__ csr, const int* __restrict__ rows,
    const unsigned short* __restrict__ Btr, const float* __restrict__ bias,
    float* __restrict__ agg, int* __restrict__ degc, int E) {
  __shared__ float4 alds[8 * 64];
  __shared__ int    olds[8 * 64];        // pre-scaled byte offsets: src*256
  __shared__ float  zl[8 * ZST];         // [dst li][kappa], stride 260
  const int w = threadIdx.x >> 6, lane = threadIdx.x & 63;
  const int j = lane >> 5, d2 = lane & 31;
  const int li = w * 2 + j;              // local dst 0..7
  const int e = blockIdx.x * 8 + li;     // grid exactly E/8

  int deg = cnt[e];
  if (deg > CAP) deg = CAP;
  float4 ad = a_dst[e];

  // softmax: slot A = neighbor d2, slot B = neighbor d2+32 (width-32)
  float exA0 = 0.f, exA1 = 0.f, exA2 = 0.f, exA3 = 0.f;
  float exB0 = 0.f, exB1 = 0.f, exB2 = 0.f, exB3 = 0.f;
  int sA = 0, sB = 0;
  if (d2 < deg) {
    sA = csr[(size_t)e * CAP + d2];
    float4 as = a_src[sA];
    float l0 = as.x + ad.x; l0 = l0 > 0.f ? l0 : 0.2f * l0;
    float l1 = as.y + ad.y; l1 = l1 > 0.f ? l1 : 0.2f * l1;
    float l2 = as.z + ad.z; l2 = l2 > 0.f ? l2 : 0.2f * l2;
    float l3 = as.w + ad.w; l3 = l3 > 0.f ? l3 : 0.2f * l3;
    exA0 = __expf(l0); exA1 = __expf(l1); exA2 = __expf(l2); exA3 = __expf(l3);
  }
  if (deg > 32 && d2 + 32 < deg) {
    sB = csr[(size_t)e * CAP + d2 + 32];
    float4 as = a_src[sB];
    float l0 = as.x + ad.x; l0 = l0 > 0.f ? l0 : 0.2f * l0;
    float l1 = as.y + ad.y; l1 = l1 > 0.f ? l1 : 0.2f * l1;
    float l2 = as.z + ad.z; l2 = l2 > 0.f ? l2 : 0.2f * l2;
    float l3 = as.w + ad.w; l3 = l3 > 0.f ? l3 : 0.2f * l3;
    exB0 = __expf(l0); exB1 = __expf(l1); exB2 = __expf(l2); exB3 = __expf(l3);
  }
  float s0 = exA0 + exB0, s1 = exA1 + exB1;
  float s2 = exA2 + exB2, s3 = exA3 + exB3;
#pragma unroll
  for (int off = 16; off > 0; off >>= 1) {
    s0 += __shfl_xor(s0, off, 64);
    s1 += __shfl_xor(s1, off, 64);
    s2 += __shfl_xor(s2, off, 64);
    s3 += __shfl_xor(s3, off, 64);
  }
  float i0 = 1.f / (s0 + 1e-16f), i1 = 1.f / (s1 + 1e-16f);
  float i2 = 1.f / (s2 + 1e-16f), i3 = 1.f / (s3 + 1e-16f);

  // half-private staging: no barrier needed (only this half reads kb slice)
  alds[li * 64 + d2] = make_float4(exA0 * i0, exA1 * i1, exA2 * i2, exA3 * i3);
  olds[li * 64 + d2] = sA << 8;          // fp32 x row = 256 bytes
  if (deg > 32) {
    alds[li * 64 + d2 + 32] =
        make_float4(exB0 * i0, exB1 * i1, exB2 * i2, exB3 * i3);
    olds[li * 64 + d2 + 32] = sB << 8;
  }

  // gather: half walks its dst's neighbors serially, 4-deep pipelined.
  // lane (j,d2) accumulates dims 2*d2, 2*d2+1 for 4 heads.
  const char* xrow = (const char*)x + d2 * 8;
  const int kb = li * 64;
  f32x2 zz0 = {0.f, 0.f}, zz1 = {0.f, 0.f}, zz2 = {0.f, 0.f}, zz3 = {0.f, 0.f};

#define LD(K) (*(const float2*)(xrow + (size_t)(unsigned)olds[kb + (K)]))
#define CONS(K, V) { \
    float4 A_ = alds[kb + (K)]; \
    f32x2 xv_; xv_.x = (V).x; xv_.y = (V).y; \
    f32x2 c0_ = {A_.x, A_.x}, c1_ = {A_.y, A_.y}; \
    f32x2 c2_ = {A_.z, A_.z}, c3_ = {A_.w, A_.w}; \
    zz0 += c0_ * xv_; zz1 += c1_ * xv_; zz2 += c2_ * xv_; zz3 += c3_ * xv_; }

  int k = 0;
  if (deg >= 4) {
    float2 v0 = LD(0), v1 = LD(1), v2 = LD(2), v3 = LD(3);
    for (; k + 8 <= deg; k += 4) {
      float2 n0 = LD(k + 4), n1 = LD(k + 5), n2 = LD(k + 6), n3 = LD(k + 7);
      CONS(k, v0) CONS(k + 1, v1) CONS(k + 2, v2) CONS(k + 3, v3)
      v0 = n0; v1 = n1; v2 = n2; v3 = n3;
    }
    CONS(k, v0) CONS(k + 1, v1) CONS(k + 2, v2) CONS(k + 3, v3)
    k += 4;
  }
  for (; k < deg; ++k) {
    float2 v = LD(k);
    CONS(k, v)
  }
#undef LD
#undef CONS

  // stage z: lane (li,d2) holds dims 2d2,2d2+1 x 4 heads (kappa = h*64+dim)
  {
    float* zw = &zl[li * ZST + 2 * d2];
    *(float2*)&zw[0]   = make_float2(zz0.x, zz0.y);
    *(float2*)&zw[64]  = make_float2(zz1.x, zz1.y);
    *(float2*)&zw[128] = make_float2(zz2.x, zz2.y);
    *(float2*)&zw[192] = make_float2(zz3.x, zz3.y);
  }
  __syncthreads();

  // epilogue: out[8 dst][64 c] = z @ Btr^T ; wave w -> col tile w (c=w*16+l15)
  const int l15 = lane & 15, l4 = lane >> 4;
  const int drow = l15 & 7;              // A row content: dst 0..7 (8..15 dup)
  const unsigned short* bp = Btr + (size_t)(w * 16 + l15) * 256 + l4 * 8;
  const float* zp = &zl[drow * ZST + l4 * 8];
  f32x4 acc = {0.f, 0.f, 0.f, 0.f};
#pragma unroll
  for (int kk = 0; kk < 8; ++kk) {
    const float4* z4p = (const float4*)(zp + kk * 32);
    float4 za = z4p[0], zb = z4p[1];
    frag16 af;
    unsigned* au = (unsigned*)&af;
    au[0] = pkbf(za.x, za.y);
    au[1] = pkbf(za.z, za.w);
    au[2] = pkbf(zb.x, zb.y);
    au[3] = pkbf(zb.z, zb.w);
    frag16 bfg = *(const frag16*)(bp + kk * 32);
    acc = __builtin_amdgcn_mfma_f32_16x16x32_bf16(af, bfg, acc, 0, 0, 0);
  }
  // C map: row = l4*4 + reg, col = l15 -> rows 0..7 live in lanes l4 < 2
  if (l4 < 2) {
    int ccol = w * 16 + l15;
    float bs = bias[ccol];
#pragma unroll
    for (int r = 0; r < 4; ++r) {
      int ee = blockIdx.x * 8 + l4 * 4 + r;
      atomicAdd(&agg[(size_t)rows[ee] * 64 + ccol], acc[r] + bs);
    }
  }
  if (d2 == 0) atomicAdd(&degc[rows[e]], 1);
}

// ---------------- scatter-mean normalize + final linear ----------------
__global__ __launch_bounds__(256) void k_final(
    const float* __restrict__ agg, const int* __restrict__ degc,
    const float* __restrict__ wgt, const float* __restrict__ wb,
    float* __restrict__ out, int N) {
  __shared__ float wtt[64 * 65];
  const int t = threadIdx.x;
#pragma unroll
  for (int i = 0; i < 16; ++i) {
    int idx = t + i * 256;                       // idx = c*64 + k
    wtt[(idx & 63) * 65 + (idx >> 6)] = wgt[idx];
  }
  __syncthreads();
  const int w = t >> 6, lane = t & 63;
  int n = blockIdx.x * 4 + w;
  if (n >= N) return;
  int dg = degc[n];
  float av = dg > 0 ? agg[(size_t)n * 64 + lane] / (float)dg : 0.f;
  float o = 0.f;
#pragma unroll
  for (int k = 0; k < 64; ++k) {
    o += __shfl(av, k, 64) * wtt[k * 65 + lane];
  }
  out[(size_t)n * 64 + lane] = o + wb[lane];
}

extern "C" void kernel_launch(void* const* d_in, const int* in_sizes, int n_in,
                              void* d_out, int out_size, void* d_ws, size_t ws_size,
                              hipStream_t stream) {
  const float* x       = (const float*)d_in[0];
  const int*   ei      = (const int*)d_in[1];
  const int*   rows    = (const int*)d_in[2];
  const float* W       = (const float*)d_in[3];
  const float* att_src = (const float*)d_in[4];
  const float* att_dst = (const float*)d_in[5];
  const float* bias    = (const float*)d_in[6];
  const float* wgt     = (const float*)d_in[7];
  const float* wb      = (const float*)d_in[8];

  const int E = in_sizes[0] / 64;     // 131072
  const int M = in_sizes[1] / 2;      // 2097152
  const int N = out_size / 64;        // 16384

  char* p = (char*)d_ws;
  int*   csr   = (int*)p;                   p += (size_t)E * CAP * 4;  // 32MB
  float* a_src = (float*)p;                 p += (size_t)E * 4 * 4;    // 2MB
  float* a_dst = (float*)p;                 p += (size_t)E * 4 * 4;    // 2MB
  // cnt, agg, degc contiguous -> single memset
  int*   cnt   = (int*)p;                   p += (size_t)E * 4;        // 512KB
  float* agg   = (float*)p;                 p += (size_t)N * 64 * 4;   // 4MB
  int*   degc  = (int*)p;                   p += (size_t)N * 4;        // 64KB
  unsigned short* Btr = (unsigned short*)p; p += 64 * 256 * 2;         // 32KB
  float* vs    = (float*)p;                 p += 512 * 4;              // 2KB

  hipMemsetAsync(cnt, 0,
                 (size_t)E * 4 + (size_t)N * 64 * 4 + (size_t)N * 4, stream);

  k_prevs<<<64, 256, 0, stream>>>(W, att_src, att_dst, Btr, vs);

  const int Mtot = M + E;
  const int ncast = E / 64;                  // 2048
  const int nfill = (Mtot + 1023) / 1024;    // 2176
  k_fused<<<ncast + nfill, 256, 0, stream>>>(
      x, vs, a_src, a_dst, ei, M, E, cnt, csr, ncast, nfill);

  k_agg<<<E / 8, 256, 0, stream>>>(
      x, (const float4*)a_src, (const float4*)a_dst, cnt, csr,
      rows, Btr, bias, agg, degc, E);

  k_final<<<(N + 3) / 4, 256, 0, stream>>>(agg, degc, wgt, wb, (float*)d_out, N);
}

// Round 13
// 236.829 us; speedup vs baseline: 1.5628x; 1.0654x over previous
//
#include <hip/hip_runtime.h>
#include <hip/hip_bf16.h>

// GAT on line graph. Pipeline (round 13):
//   k_prevs : Btr[c][kap]=0.25*W bf16 ; vs[8][64]=W^T@att
//   k_fused : heterogeneous grid: adot blocks (exact fp32 a_src/a_dst from x)
//             paired with fill blocks (CSR bucket, 4 edges/thr).
//   k_agg   : 4 dsts per wave (16-lane quarters): width-16 softmax (4 slots),
//             4-deep-pipelined fp32 x-row gather (float4/lane, one global
//             load instruction serves 4 edges), bf16 zl staging, 16-dst MFMA
//             epilogue (A row = dst), 64-wide agg atomics.
//   k_final : scatter-mean normalize + 64x64 linear

#define CAP 64
#define ZLS 264   // zl bf16 stride (264*2B = 528B; word-stride mod 32 = 4)

using frag16 = __attribute__((ext_vector_type(8))) short;  // 8 bf16
using f32x4  = __attribute__((ext_vector_type(4))) float;
using f32x2  = __attribute__((ext_vector_type(2))) float;

__device__ __forceinline__ unsigned short f2bf(float f) {
  union { float f; unsigned u; } v; v.f = f;
  return (unsigned short)((v.u + 0x8000u) >> 16);
}
__device__ __forceinline__ unsigned pkbf(float lo, float hi) {
  union { __hip_bfloat162 b; unsigned u; } v;
  v.b = __float22bfloat162_rn(make_float2(lo, hi));   // v_cvt_pk_bf16_f32
  return v.u;
}

// ---------------- Pass 0: vs + Btr precompute ----------------
__global__ __launch_bounds__(256) void k_prevs(
    const float* __restrict__ W, const float* __restrict__ att_src,
    const float* __restrict__ att_dst, unsigned short* __restrict__ Btr,
    float* __restrict__ vs) {
  int t = blockIdx.x * 256 + threadIdx.x;    // 64 blocks -> 16384
  {
    int c = t >> 8, kap = t & 255;           // Btr[c][kap] = 0.25*W[h*64+c][k]
    int h = kap >> 6, k = kap & 63;
    Btr[t] = f2bf(0.25f * W[(size_t)(h * 64 + c) * 64 + k]);
  }
  if (blockIdx.x < 2) {
    int o = blockIdx.x * 256 + threadIdx.x;  // 0..511
    int j = o >> 6, c = o & 63;              // 0..3 src heads, 4..7 dst heads
    const float* att = (j < 4) ? att_src : att_dst;
    int hh = j & 3;
    float s = 0.f;
    for (int ch = 0; ch < 64; ++ch)
      s += W[(size_t)(hh * 64 + ch) * 64 + c] * att[hh * 64 + ch];
    vs[o] = s;
  }
}

// ---------------- Fused: a-dot blocks + fill blocks ----------------
__device__ __forceinline__ void adot_body(
    const float* __restrict__ x, const float* __restrict__ vs,
    float* __restrict__ a_src, float* __restrict__ a_dst, int bid,
    float* vsl) {
  const int t = threadIdx.x;
  if (t < 128) ((float4*)vsl)[t] = ((const float4*)vs)[t];
  __syncthreads();
  const int w = t >> 6, lane = t & 63, l15 = lane & 15, l4 = lane >> 4;
  const int row = bid * 64 + w * 16 + l15;

  const float4* xp = (const float4*)(x + (size_t)row * 64 + l4 * 16);
  float4 v0 = xp[0], v1 = xp[1], v2 = xp[2], v3 = xp[3];
  float xa[16] = {v0.x, v0.y, v0.z, v0.w, v1.x, v1.y, v1.z, v1.w,
                  v2.x, v2.y, v2.z, v2.w, v3.x, v3.y, v3.z, v3.w};

  float pj[8];
#pragma unroll
  for (int j = 0; j < 8; ++j) {
    const float4* q = (const float4*)(vsl + j * 64 + l4 * 16);
    float4 q0 = q[0], q1 = q[1], q2 = q[2], q3 = q[3];
    float s = xa[0] * q0.x + xa[1] * q0.y + xa[2] * q0.z + xa[3] * q0.w
            + xa[4] * q1.x + xa[5] * q1.y + xa[6] * q1.z + xa[7] * q1.w
            + xa[8] * q2.x + xa[9] * q2.y + xa[10] * q2.z + xa[11] * q2.w
            + xa[12] * q3.x + xa[13] * q3.y + xa[14] * q3.z + xa[15] * q3.w;
    s += __shfl_xor(s, 16, 64);
    s += __shfl_xor(s, 32, 64);
    pj[j] = s;
  }
  if (l4 == 0) {
    *(float4*)&a_src[(size_t)row * 4] = make_float4(pj[0], pj[1], pj[2], pj[3]);
    *(float4*)&a_dst[(size_t)row * 4] = make_float4(pj[4], pj[5], pj[6], pj[7]);
  }
}

__device__ __forceinline__ void fill_body(
    const int* __restrict__ ei, int M, int E,
    int* __restrict__ cnt, int* __restrict__ csr, int bid) {
  const int Mtot = M + E;
  const int base = bid * 1024 + threadIdx.x;
  int mm[4], ss[4], dd[4];
#pragma unroll
  for (int i = 0; i < 4; ++i) {
    int m = base + i * 256;
    mm[i] = m;
    if (m < Mtot) {
      if (m < M) { ss[i] = ei[m]; dd[i] = ei[M + m]; }
      else       { ss[i] = m - M; dd[i] = m - M; }   // self loop
    }
  }
  int pos[4];
#pragma unroll
  for (int i = 0; i < 4; ++i)
    if (mm[i] < Mtot) pos[i] = atomicAdd(&cnt[dd[i]], 1);
#pragma unroll
  for (int i = 0; i < 4; ++i)
    if (mm[i] < Mtot && pos[i] < CAP) csr[(size_t)dd[i] * CAP + pos[i]] = ss[i];
}

__global__ __launch_bounds__(256, 4) void k_fused(
    const float* __restrict__ x, const float* __restrict__ vs,
    float* __restrict__ a_src, float* __restrict__ a_dst,
    const int* __restrict__ ei, int M, int E,
    int* __restrict__ cnt, int* __restrict__ csr,
    int ncast, int nfill) {
  __shared__ float vsl[512];
  const int bid = blockIdx.x;
  int npair = 2 * min(ncast, nfill);
  if (bid < npair) {
    if (bid & 1) adot_body(x, vs, a_src, a_dst, bid >> 1, vsl);
    else         fill_body(ei, M, E, cnt, csr, bid >> 1);
  } else {
    int r = bid - npair;
    if (nfill > ncast) fill_body(ei, M, E, cnt, csr, ncast + r);
    else               adot_body(x, vs, a_src, a_dst, ncast + r, vsl);
  }
}

// --- Aggregation: 4 dsts/wave softmax + pipelined float4 gather + MFMA -----
__global__ __launch_bounds__(256) void k_agg(
    const float* __restrict__ x, const float4* __restrict__ a_src,
    const float4* __restrict__ a_dst, const int* __restrict__ cnt,
    const int* __restrict__ csr, const int* __restrict__ rows,
    const unsigned short* __restrict__ Btr, const float* __restrict__ bias,
    float* __restrict__ agg, int* __restrict__ degc, int E) {
  __shared__ float4 alds[16 * 64];            // 16KB: normalized alpha
  __shared__ int    olds[16 * 64];            // 4KB: byte offsets src*256
  __shared__ unsigned short zl[16 * ZLS];     // 8.25KB: z staged bf16
  const int w = threadIdx.x >> 6, lane = threadIdx.x & 63;
  const int q = lane >> 4, d4 = lane & 15;
  const int li = w * 4 + q;              // local dst 0..15
  const int e = blockIdx.x * 16 + li;    // grid exactly E/16

  int deg = cnt[e];
  if (deg > CAP) deg = CAP;
  float4 ad = a_dst[e];

  // softmax: 4 slots per lane (k = d4 + 16*s), width-16 reduce
  float exs[4][4];
  int   srcs[4];
  float s0 = 0.f, s1 = 0.f, s2 = 0.f, s3 = 0.f;
#pragma unroll
  for (int s = 0; s < 4; ++s) {
    int k = d4 + s * 16;
    float e0 = 0.f, e1 = 0.f, e2 = 0.f, e3 = 0.f;
    int sk = 0;
    if (k < deg) {
      sk = csr[(size_t)e * CAP + k];
      float4 as = a_src[sk];
      float l0 = as.x + ad.x; l0 = l0 > 0.f ? l0 : 0.2f * l0;
      float l1 = as.y + ad.y; l1 = l1 > 0.f ? l1 : 0.2f * l1;
      float l2 = as.z + ad.z; l2 = l2 > 0.f ? l2 : 0.2f * l2;
      float l3 = as.w + ad.w; l3 = l3 > 0.f ? l3 : 0.2f * l3;
      e0 = __expf(l0); e1 = __expf(l1); e2 = __expf(l2); e3 = __expf(l3);
    }
    srcs[s] = sk;
    exs[s][0] = e0; exs[s][1] = e1; exs[s][2] = e2; exs[s][3] = e3;
    s0 += e0; s1 += e1; s2 += e2; s3 += e3;
  }
#pragma unroll
  for (int off = 8; off > 0; off >>= 1) {
    s0 += __shfl_xor(s0, off, 64);
    s1 += __shfl_xor(s1, off, 64);
    s2 += __shfl_xor(s2, off, 64);
    s3 += __shfl_xor(s3, off, 64);
  }
  float i0 = 1.f / (s0 + 1e-16f), i1 = 1.f / (s1 + 1e-16f);
  float i2 = 1.f / (s2 + 1e-16f), i3 = 1.f / (s3 + 1e-16f);

  // quarter-private staging: no barrier needed
#pragma unroll
  for (int s = 0; s < 4; ++s) {
    int k = d4 + s * 16;
    if (k < deg) {
      alds[li * 64 + k] = make_float4(exs[s][0] * i0, exs[s][1] * i1,
                                      exs[s][2] * i2, exs[s][3] * i3);
      olds[li * 64 + k] = srcs[s] << 8;  // fp32 x row = 256 bytes
    }
  }

  // gather: quarter walks its dst's neighbors serially, 4-deep pipelined.
  // lane (li,d4) accumulates dims 4*d4 .. 4*d4+3 for 4 heads.
  const char* xrow = (const char*)x + d4 * 16;
  const int kb = li * 64;
  f32x2 z0a = {0.f, 0.f}, z0b = {0.f, 0.f}, z1a = {0.f, 0.f}, z1b = {0.f, 0.f};
  f32x2 z2a = {0.f, 0.f}, z2b = {0.f, 0.f}, z3a = {0.f, 0.f}, z3b = {0.f, 0.f};

#define LD(K) (*(const float4*)(xrow + (size_t)(unsigned)olds[kb + (K)]))
#define CONS(K, V) { \
    float4 A_ = alds[kb + (K)]; \
    f32x2 xa_; xa_.x = (V).x; xa_.y = (V).y; \
    f32x2 xb_; xb_.x = (V).z; xb_.y = (V).w; \
    f32x2 c0_ = {A_.x, A_.x}, c1_ = {A_.y, A_.y}; \
    f32x2 c2_ = {A_.z, A_.z}, c3_ = {A_.w, A_.w}; \
    z0a += c0_ * xa_; z0b += c0_ * xb_; \
    z1a += c1_ * xa_; z1b += c1_ * xb_; \
    z2a += c2_ * xa_; z2b += c2_ * xb_; \
    z3a += c3_ * xa_; z3b += c3_ * xb_; }

  int k = 0;
  if (deg >= 4) {
    float4 v0 = LD(0), v1 = LD(1), v2 = LD(2), v3 = LD(3);
    for (; k + 8 <= deg; k += 4) {
      float4 n0 = LD(k + 4), n1 = LD(k + 5), n2 = LD(k + 6), n3 = LD(k + 7);
      CONS(k, v0) CONS(k + 1, v1) CONS(k + 2, v2) CONS(k + 3, v3)
      v0 = n0; v1 = n1; v2 = n2; v3 = n3;
    }
    CONS(k, v0) CONS(k + 1, v1) CONS(k + 2, v2) CONS(k + 3, v3)
    k += 4;
  }
  for (; k < deg; ++k) {
    float4 v = LD(k);
    CONS(k, v)
  }
#undef LD
#undef CONS

  // stage z as bf16: lane (li,d4) -> zl[li][h*64 + 4*d4 .. +3]
  {
    unsigned short* zw = &zl[li * ZLS + 4 * d4];
    *(uint2*)&zw[0 * 64] = make_uint2(pkbf(z0a.x, z0a.y), pkbf(z0b.x, z0b.y));
    *(uint2*)&zw[1 * 64] = make_uint2(pkbf(z1a.x, z1a.y), pkbf(z1b.x, z1b.y));
    *(uint2*)&zw[2 * 64] = make_uint2(pkbf(z2a.x, z2a.y), pkbf(z2b.x, z2b.y));
    *(uint2*)&zw[3 * 64] = make_uint2(pkbf(z3a.x, z3a.y), pkbf(z3b.x, z3b.y));
  }
  __syncthreads();

  // epilogue: out[16 dst][64 c] = z @ Btr^T; wave w -> col tile (c=w*16+l15);
  // A row l15 = dst l15 (exact, no duplication).
  const int l15 = lane & 15, l4 = lane >> 4;
  const unsigned short* bp = Btr + (size_t)(w * 16 + l15) * 256 + l4 * 8;
  const unsigned short* zp = &zl[l15 * ZLS + l4 * 8];
  f32x4 acc = {0.f, 0.f, 0.f, 0.f};
#pragma unroll
  for (int kk = 0; kk < 8; ++kk) {
    frag16 af  = *(const frag16*)(zp + kk * 32);
    frag16 bfg = *(const frag16*)(bp + kk * 32);
    acc = __builtin_amdgcn_mfma_f32_16x16x32_bf16(af, bfg, acc, 0, 0, 0);
  }
  // C map: row = l4*4 + reg, col = l15 -> all 64 lanes write 4 dsts each
  {
    int ccol = w * 16 + l15;
    float bs = bias[ccol];
#pragma unroll
    for (int r = 0; r < 4; ++r) {
      int ee = blockIdx.x * 16 + l4 * 4 + r;
      atomicAdd(&agg[(size_t)rows[ee] * 64 + ccol], acc[r] + bs);
    }
  }
  if (d4 == 0) atomicAdd(&degc[rows[e]], 1);
}

// ---------------- scatter-mean normalize + final linear ----------------
__global__ __launch_bounds__(256) void k_final(
    const float* __restrict__ agg, const int* __restrict__ degc,
    const float* __restrict__ wgt, const float* __restrict__ wb,
    float* __restrict__ out, int N) {
  __shared__ float wtt[64 * 65];
  const int t = threadIdx.x;
#pragma unroll
  for (int i = 0; i < 16; ++i) {
    int idx = t + i * 256;                       // idx = c*64 + k
    wtt[(idx & 63) * 65 + (idx >> 6)] = wgt[idx];
  }
  __syncthreads();
  const int w = t >> 6, lane = t & 63;
  int n = blockIdx.x * 4 + w;
  if (n >= N) return;
  int dg = degc[n];
  float av = dg > 0 ? agg[(size_t)n * 64 + lane] / (float)dg : 0.f;
  float o = 0.f;
#pragma unroll
  for (int k = 0; k < 64; ++k) {
    o += __shfl(av, k, 64) * wtt[k * 65 + lane];
  }
  out[(size_t)n * 64 + lane] = o + wb[lane];
}

extern "C" void kernel_launch(void* const* d_in, const int* in_sizes, int n_in,
                              void* d_out, int out_size, void* d_ws, size_t ws_size,
                              hipStream_t stream) {
  const float* x       = (const float*)d_in[0];
  const int*   ei      = (const int*)d_in[1];
  const int*   rows    = (const int*)d_in[2];
  const float* W       = (const float*)d_in[3];
  const float* att_src = (const float*)d_in[4];
  const float* att_dst = (const float*)d_in[5];
  const float* bias    = (const float*)d_in[6];
  const float* wgt     = (const float*)d_in[7];
  const float* wb      = (const float*)d_in[8];

  const int E = in_sizes[0] / 64;     // 131072
  const int M = in_sizes[1] / 2;      // 2097152
  const int N = out_size / 64;        // 16384

  char* p = (char*)d_ws;
  int*   csr   = (int*)p;                   p += (size_t)E * CAP * 4;  // 32MB
  float* a_src = (float*)p;                 p += (size_t)E * 4 * 4;    // 2MB
  float* a_dst = (float*)p;                 p += (size_t)E * 4 * 4;    // 2MB
  // cnt, agg, degc contiguous -> single memset
  int*   cnt   = (int*)p;                   p += (size_t)E * 4;        // 512KB
  float* agg   = (float*)p;                 p += (size_t)N * 64 * 4;   // 4MB
  int*   degc  = (int*)p;                   p += (size_t)N * 4;        // 64KB
  unsigned short* Btr = (unsigned short*)p; p += 64 * 256 * 2;         // 32KB
  float* vs    = (float*)p;                 p += 512 * 4;              // 2KB

  hipMemsetAsync(cnt, 0,
                 (size_t)E * 4 + (size_t)N * 64 * 4 + (size_t)N * 4, stream);

  k_prevs<<<64, 256, 0, stream>>>(W, att_src, att_dst, Btr, vs);

  const int Mtot = M + E;
  const int ncast = E / 64;                  // 2048
  const int nfill = (Mtot + 1023) / 1024;    // 2176
  k_fused<<<ncast + nfill, 256, 0, stream>>>(
      x, vs, a_src, a_dst, ei, M, E, cnt, csr, ncast, nfill);

  k_agg<<<E / 16, 256, 0, stream>>>(
      x, (const float4*)a_src, (const float4*)a_dst, cnt, csr,
      rows, Btr, bias, agg, degc, E);

  k_final<<<(N + 3) / 4, 256, 0, stream>>>(agg, degc, wgt, wb, (float*)d_out, N);
}